// Round 11
// baseline (535.079 us; speedup 1.0000x reference)
//
#include <hip/hip_runtime.h>
#include <hip/hip_bf16.h>

typedef __attribute__((ext_vector_type(8))) short short8;
typedef __attribute__((ext_vector_type(4))) short s16x4;
typedef __attribute__((ext_vector_type(4))) float f32x4;

// fp32 -> bf16 bits, round-to-nearest-even
static __device__ inline short f2bf(float f) {
    unsigned u = __float_as_uint(f);
    unsigned r = (u + 0x7fffu + ((u >> 16) & 1u)) >> 16;
    return (short)r;
}
static __device__ inline float bf2f(short h) {
    return __uint_as_float(((unsigned)(unsigned short)h) << 16);
}

// Swizzled LDS short-offset for 32-short (64B) rows; 16B slot in 0..3.
static __device__ inline int swz32(int row, int slot) {
    return row * 32 + ((slot ^ ((row >> 1) & 3)) << 3);
}
// For 64-short (128B) rows; 16B slot in 0..7.
static __device__ inline int swz64(int row, int slot) {
    return row * 64 + ((slot ^ (row & 7)) << 3);
}

// Device-scope grid barrier: monotonic counter, all blocks co-resident
// (grid <= 256 blocks on 256 CUs). Bounded spin for hang-safety.
static __device__ inline void gbar(unsigned* cnt, unsigned target) {
    __syncthreads();
    if (threadIdx.x == 0) {
        __threadfence();   // release: prior global writes visible device-wide
        __hip_atomic_fetch_add(cnt, 1u, __ATOMIC_ACQ_REL, __HIP_MEMORY_SCOPE_AGENT);
        long guard = 0;
        while (__hip_atomic_load(cnt, __ATOMIC_ACQUIRE, __HIP_MEMORY_SCOPE_AGENT) < target) {
            __builtin_amdgcn_s_sleep(2);
            if (++guard > (1L << 25)) break;
        }
        __threadfence();   // acquire
    }
    __syncthreads();
}

// Fused: row norms + scale + bf16 cast, row-major and transposed writes.
__global__ __launch_bounds__(256) void k_prepall(const float* __restrict__ vec,
                                                 short* __restrict__ Vh,
                                                 short* __restrict__ Vth,
                                                 int m, int dim) {
    __shared__ float tile[8][1028];
    __shared__ float ps[8][32];
    __shared__ float invs[8];
    int r0 = blockIdx.x * 8;
    int t = threadIdx.x;
    int rt = t >> 5, ct = t & 31;
    float ss = 0.f;
#pragma unroll
    for (int p = 0; p < 8; ++p) {
        int c = p * 128 + ct * 4;
        float4 v = *(const float4*)&vec[(size_t)(r0 + rt) * dim + c];
        *(float4*)&tile[rt][c] = v;
        ss += v.x * v.x + v.y * v.y + v.z * v.z + v.w * v.w;
    }
    ps[rt][ct] = ss;
    __syncthreads();
    if (t < 8) {
        float s = 0.f;
#pragma unroll
        for (int q = 0; q < 32; ++q) s += ps[t][q];
        invs[t] = 1.0f / sqrtf(s);
    }
    __syncthreads();
    float iv = invs[rt];
#pragma unroll
    for (int p = 0; p < 8; ++p) {
        int c = p * 128 + ct * 4;
        s16x4 h;
#pragma unroll
        for (int q = 0; q < 4; ++q) h[q] = f2bf(tile[rt][c + q] * iv);
        *(s16x4*)&Vh[(size_t)(r0 + rt) * dim + c] = h;
    }
#pragma unroll
    for (int cc = 0; cc < 4; ++cc) {
        int c = t * 4 + cc;
        s16x4 h0, h1;
#pragma unroll
        for (int r = 0; r < 4; ++r) h0[r] = f2bf(tile[r][c] * invs[r]);
#pragma unroll
        for (int r = 0; r < 4; ++r) h1[r] = f2bf(tile[4 + r][c] * invs[4 + r]);
        *(s16x4*)&Vth[(size_t)c * m + r0] = h0;
        *(s16x4*)&Vth[(size_t)c * m + r0 + 4] = h1;
    }
}

// 64x64-tile NT GEMM, bf16 operands, register-prefetch double buffering.
// CH chains; MODE/TRI as before. Extra blocks run fused cast; first cast
// block also zeroes the tree barrier counter.
template<int MODE, int TRI, int CH>
__global__ __launch_bounds__(256) void k_nt64pc(
    const short* __restrict__ Ah, const short* __restrict__ Al,
    const short* __restrict__ Bh, const short* __restrict__ Bl,
    float* __restrict__ Cf, short* __restrict__ Ch, short* __restrict__ Cl,
    int K, int lda, int ldb, int ldc, int gw, int nTiles,
    const float* __restrict__ castX, short* __restrict__ castXh, int castN4,
    unsigned* zeroCnt) {
    __shared__ short As[2][2][64 * 32];
    __shared__ short Bs[2][2][64 * 32];
    int flat = blockIdx.x;
    if (flat >= nTiles) {
        if (zeroCnt && flat == nTiles && threadIdx.x == 0) *zeroCnt = 0u;
        int idx = (flat - nTiles) * 256 + threadIdx.x;
        int stride = (gridDim.x - nTiles) * 256;
        for (int i = idx; i < castN4; i += stride) {
            float4 v = ((const float4*)castX)[i];
            float f[4] = {v.x, v.y, v.z, v.w};
            s16x4 h;
#pragma unroll
            for (int q = 0; q < 4; ++q) h[q] = f2bf(f[q]);
            *(s16x4*)&castXh[(size_t)i * 4] = h;
        }
        return;
    }
    int i0 = (flat / gw) * 64, j0 = (flat % gw) * 64;
    if (TRI == 2 && j0 < i0) return;
    int KE = (TRI == 1) ? (j0 + 64) : K;
    int t = threadIdx.x, lane = t & 63, wave = t >> 6;
    int wr = wave >> 1, wc = wave & 1;
    int srow = t >> 2, slot = t & 3;
    int sofs = swz32(srow, slot);
    int gofs = slot * 8;
    const short* gA_h = &Ah[(size_t)(i0 + srow) * lda + gofs];
    const short* gA_l = (CH >= 3) ? &Al[(size_t)(i0 + srow) * lda + gofs] : nullptr;
    const short* gB_h = &Bh[(size_t)(j0 + srow) * ldb + gofs];
    const short* gB_l = (CH >= 2) ? &Bl[(size_t)(j0 + srow) * ldb + gofs] : nullptr;
    short8 pAh = *(const short8*)&gA_h[0];
    short8 pAl, pBl;
    short8 pBh = *(const short8*)&gB_h[0];
    if (CH >= 2) pBl = *(const short8*)&gB_l[0];
    if (CH >= 3) pAl = *(const short8*)&gA_l[0];
    *(short8*)&As[0][0][sofs] = pAh;
    *(short8*)&Bs[0][0][sofs] = pBh;
    if (CH >= 2) *(short8*)&Bs[0][1][sofs] = pBl;
    if (CH >= 3) *(short8*)&As[0][1][sofs] = pAl;
    f32x4 acc[2][2] = {};
    int nIter = KE >> 5;
    int cur = 0;
    for (int it = 0; it < nIter; ++it) {
        __syncthreads();
        int kn = (it + 1) << 5;
        bool have = kn < KE;
        if (have) {
            pAh = *(const short8*)&gA_h[kn];
            pBh = *(const short8*)&gB_h[kn];
            if (CH >= 2) pBl = *(const short8*)&gB_l[kn];
            if (CH >= 3) pAl = *(const short8*)&gA_l[kn];
        }
        int g = lane >> 4;
        short8 ah[2], al2[2], bh[2], bl2[2];
#pragma unroll
        for (int i = 0; i < 2; ++i) {
            int ro = swz32(wr * 32 + i * 16 + (lane & 15), g);
            ah[i] = *(const short8*)&As[cur][0][ro];
            if (CH >= 3) al2[i] = *(const short8*)&As[cur][1][ro];
        }
#pragma unroll
        for (int j = 0; j < 2; ++j) {
            int ro = swz32(wc * 32 + j * 16 + (lane & 15), g);
            bh[j] = *(const short8*)&Bs[cur][0][ro];
            if (CH >= 2) bl2[j] = *(const short8*)&Bs[cur][1][ro];
        }
#pragma unroll
        for (int i = 0; i < 2; ++i)
#pragma unroll
            for (int j = 0; j < 2; ++j) {
                acc[i][j] = __builtin_amdgcn_mfma_f32_16x16x32_bf16(ah[i], bh[j], acc[i][j], 0, 0, 0);
                if (CH >= 2)
                    acc[i][j] = __builtin_amdgcn_mfma_f32_16x16x32_bf16(ah[i], bl2[j], acc[i][j], 0, 0, 0);
                if (CH >= 3)
                    acc[i][j] = __builtin_amdgcn_mfma_f32_16x16x32_bf16(al2[i], bh[j], acc[i][j], 0, 0, 0);
            }
        if (have) {
            *(short8*)&As[cur ^ 1][0][sofs] = pAh;
            *(short8*)&Bs[cur ^ 1][0][sofs] = pBh;
            if (CH >= 2) *(short8*)&Bs[cur ^ 1][1][sofs] = pBl;
            if (CH >= 3) *(short8*)&As[cur ^ 1][1][sofs] = pAl;
        }
        cur ^= 1;
    }
#pragma unroll
    for (int i = 0; i < 2; ++i)
#pragma unroll
        for (int j = 0; j < 2; ++j) {
            int row0 = i0 + wr * 32 + i * 16 + ((lane >> 4) << 2);
            int col = j0 + wc * 32 + j * 16 + (lane & 15);
#pragma unroll
            for (int r = 0; r < 4; ++r) {
                float v = acc[i][j][r];
                size_t idx = (size_t)(row0 + r) * ldc + col;
                if (MODE == 2) {
                    Ch[idx] = f2bf((((row0 + r) == col) ? 1.f : 0.f) - v);
                } else if (MODE == 1) {
                    Ch[idx] = f2bf(v);
                } else {
                    short h = f2bf(v);
                    Ch[idx] = h;
                    Cl[idx] = f2bf(v - bf2f(h));
                    Cf[idx] = v;
                }
            }
        }
}

// trimm tile body (identical math to the verified k_trimm), LDS via pointers.
template<int PHASE>
static __device__ void trimm_tile(
    short* As0, short* As1, short* Bs0, short* Bs1,
    const short* __restrict__ Ah, const short* __restrict__ Al,
    const short* __restrict__ Bh, const short* __restrict__ Bl,
    short* __restrict__ C1h, short* __restrict__ C1l,
    short* __restrict__ C2h, short* __restrict__ C2l,
    int m, int s, int p, int r0t, int ctt) {
    int a0 = 2 * p * s, c0 = a0 + s;
    int r0 = r0t * 64, ct = ctt * 64;
    int KS = (PHASE == 1) ? 0 : r0;
    int KE = (PHASE == 1) ? (ct + 64) : s;
    size_t tbase = (size_t)p * s * s;
    int t = threadIdx.x, lane = t & 63, wave = t >> 6;
    int wr = wave >> 1, wc = wave & 1;
    int srow = t >> 2, slot = t & 3;
    int sofs = swz32(srow, slot);
    int gofs = slot * 8;
    f32x4 acc[2][2] = {};
    for (int k0 = KS; k0 < KE; k0 += 32) {
        __syncthreads();
        if (PHASE == 1) {
            *(short8*)&As0[sofs] = *(const short8*)&Ah[(size_t)(a0 + r0 + srow) * m + c0 + k0 + gofs];
            *(short8*)&As1[sofs] = *(const short8*)&Al[(size_t)(a0 + r0 + srow) * m + c0 + k0 + gofs];
            *(short8*)&Bs0[sofs] = *(const short8*)&Bh[(size_t)(c0 + ct + srow) * m + c0 + k0 + gofs];
            *(short8*)&Bs1[sofs] = *(const short8*)&Bl[(size_t)(c0 + ct + srow) * m + c0 + k0 + gofs];
        } else {
            *(short8*)&As0[sofs] = *(const short8*)&Ah[(size_t)(a0 + r0 + srow) * m + a0 + k0 + gofs];
            *(short8*)&As1[sofs] = *(const short8*)&Al[(size_t)(a0 + r0 + srow) * m + a0 + k0 + gofs];
            *(short8*)&Bs0[sofs] = *(const short8*)&Bh[tbase + (size_t)(ct + srow) * s + k0 + gofs];
            *(short8*)&Bs1[sofs] = *(const short8*)&Bl[tbase + (size_t)(ct + srow) * s + k0 + gofs];
        }
        __syncthreads();
        int g = lane >> 4;
        short8 ah[2], al2[2], bh[2], bl2[2];
#pragma unroll
        for (int i = 0; i < 2; ++i) {
            int ro = swz32(wr * 32 + i * 16 + (lane & 15), g);
            ah[i] = *(const short8*)&As0[ro];
            al2[i] = *(const short8*)&As1[ro];
        }
#pragma unroll
        for (int j = 0; j < 2; ++j) {
            int ro = swz32(wc * 32 + j * 16 + (lane & 15), g);
            bh[j] = *(const short8*)&Bs0[ro];
            bl2[j] = *(const short8*)&Bs1[ro];
        }
#pragma unroll
        for (int i = 0; i < 2; ++i)
#pragma unroll
            for (int j = 0; j < 2; ++j) {
                acc[i][j] = __builtin_amdgcn_mfma_f32_16x16x32_bf16(ah[i], bh[j], acc[i][j], 0, 0, 0);
                acc[i][j] = __builtin_amdgcn_mfma_f32_16x16x32_bf16(ah[i], bl2[j], acc[i][j], 0, 0, 0);
                acc[i][j] = __builtin_amdgcn_mfma_f32_16x16x32_bf16(al2[i], bh[j], acc[i][j], 0, 0, 0);
            }
    }
#pragma unroll
    for (int i = 0; i < 2; ++i)
#pragma unroll
        for (int j = 0; j < 2; ++j) {
            int row0 = r0 + wr * 32 + i * 16 + ((lane >> 4) << 2);
            int col = ct + wc * 32 + j * 16 + (lane & 15);
#pragma unroll
            for (int r = 0; r < 4; ++r) {
                if (PHASE == 1) {
                    float v = acc[i][j][r];
                    short h = f2bf(v);
                    short l = f2bf(v - bf2f(h));
                    size_t idx = tbase + (size_t)col * s + row0 + r;
                    C1h[idx] = h;
                    C1l[idx] = l;
                } else {
                    float v = -acc[i][j][r];
                    short h = f2bf(v);
                    short l = f2bf(v - bf2f(h));
                    int R = a0 + row0 + r, Cc = c0 + col;
                    C1h[(size_t)R * m + Cc] = h;
                    C1l[(size_t)R * m + Cc] = l;
                    C2h[(size_t)Cc * m + R] = h;
                    C2l[(size_t)Cc * m + R] = l;
                }
            }
        }
}

// Whole inversion tree in one kernel: baseinv -> s=64 fused level -> 3 trimm
// levels, separated by device-scope grid barriers. Grid = 256 blocks (all
// co-resident). Phase bodies identical to the verified standalone kernels.
__global__ __launch_bounds__(256) void k_tree_all(
    const float* __restrict__ G, const short* __restrict__ Gh, const short* __restrict__ Gl,
    short* __restrict__ Th, short* __restrict__ Tl,
    short* __restrict__ Tth, short* __restrict__ Ttl,
    short* __restrict__ tmph, short* __restrict__ tmpl,
    unsigned* cnt, int m) {
    __shared__ __align__(16) char ldsraw[66048];
    int bid = blockIdx.x;
    unsigned NB = gridDim.x;
    int t = threadIdx.x, lane = t & 63, wave = t >> 6;

    // ---- P0: invert 64x64 diagonal blocks of R = 0.5I + striu(G) ----
    {
        float* Rs = (float*)ldsraw;               // 64*64
        int d = bid >> 4, g = bid & 15;
        int b0 = d * 64;
        {
            int r = t >> 2, c00 = (t & 3) * 16;
#pragma unroll
            for (int q = 0; q < 4; ++q)
                *(float4*)&Rs[r * 64 + c00 + q * 4] =
                    *(const float4*)&G[(size_t)(b0 + r) * m + b0 + c00 + q * 4];
        }
        __syncthreads();
        int c = g * 4 + wave;
        float x = 0.f;
        for (int r = c; r >= 0; --r) {
            float s = Rs[r * 64 + lane] * x;
#pragma unroll
            for (int off = 32; off; off >>= 1) s += __shfl_xor(s, off, 64);
            if (lane == r) x = ((r == c) ? 2.f : 0.f) - 2.f * s;
        }
        short h = f2bf(x);
        short l = f2bf(x - bf2f(h));
        Th[(size_t)(b0 + lane) * m + b0 + c] = h;
        Tl[(size_t)(b0 + lane) * m + b0 + c] = l;
        Tth[(size_t)(b0 + c) * m + b0 + lane] = h;
        Ttl[(size_t)(b0 + c) * m + b0 + lane] = l;
    }
    gbar(cnt, NB * 1);

    // ---- P1: fused s=64 level (pairs 0..m/128-1) ----
    if (bid < m / 128) {
        float* Gb = (float*)ldsraw;               // 64*65
        float* Ai = Gb + 64 * 65;                 // 64*65
        float* Ci = Ai + 64 * 65;                 // 64*64
        float* Tm = Ci + 64 * 64;                 // 64*64
        int p = bid;
        int a0 = p * 128, c0 = a0 + 64;
        {
            int r = t >> 2, c00 = (t & 3) * 16;
#pragma unroll
            for (int q = 0; q < 4; ++q) {
                *(float4*)&Gb[r * 65 + c00 + q * 4] =
                    *(const float4*)&G[(size_t)(a0 + r) * m + c0 + c00 + q * 4];
                s16x4 ha = *(const s16x4*)&Th[(size_t)(a0 + r) * m + a0 + c00 + q * 4];
                s16x4 la = *(const s16x4*)&Tl[(size_t)(a0 + r) * m + a0 + c00 + q * 4];
                s16x4 hc = *(const s16x4*)&Th[(size_t)(c0 + r) * m + c0 + c00 + q * 4];
                s16x4 lc = *(const s16x4*)&Tl[(size_t)(c0 + r) * m + c0 + c00 + q * 4];
#pragma unroll
                for (int e = 0; e < 4; ++e) {
                    Ai[r * 65 + c00 + q * 4 + e] = bf2f(ha[e]) + bf2f(la[e]);
                    Ci[r * 64 + c00 + q * 4 + e] = bf2f(hc[e]) + bf2f(lc[e]);
                }
            }
        }
        __syncthreads();
        int tx = t & 15, ty = t >> 4;
        float acc[4][4] = {};
#pragma unroll 4
        for (int k = 0; k < 64; ++k) {
            float av[4], bv[4];
#pragma unroll
            for (int i = 0; i < 4; ++i) av[i] = Gb[(ty * 4 + i) * 65 + k];
#pragma unroll
            for (int j = 0; j < 4; ++j) bv[j] = Ci[k * 64 + tx * 4 + j];
#pragma unroll
            for (int i = 0; i < 4; ++i)
#pragma unroll
                for (int j = 0; j < 4; ++j) acc[i][j] += av[i] * bv[j];
        }
#pragma unroll
        for (int i = 0; i < 4; ++i)
#pragma unroll
            for (int j = 0; j < 4; ++j) Tm[(ty * 4 + i) * 64 + tx * 4 + j] = acc[i][j];
        __syncthreads();
        float acc2[4][4] = {};
#pragma unroll 4
        for (int k = 0; k < 64; ++k) {
            float av[4], bv[4];
#pragma unroll
            for (int i = 0; i < 4; ++i) av[i] = Ai[(ty * 4 + i) * 65 + k];
#pragma unroll
            for (int j = 0; j < 4; ++j) bv[j] = Tm[k * 64 + tx * 4 + j];
#pragma unroll
            for (int i = 0; i < 4; ++i)
#pragma unroll
                for (int j = 0; j < 4; ++j) acc2[i][j] += av[i] * bv[j];
        }
#pragma unroll
        for (int i = 0; i < 4; ++i)
#pragma unroll
            for (int j = 0; j < 4; ++j) {
                float v = -acc2[i][j];
                short h = f2bf(v);
                short l = f2bf(v - bf2f(h));
                int R = a0 + ty * 4 + i, C = c0 + tx * 4 + j;
                Th[(size_t)R * m + C] = h;
                Tl[(size_t)R * m + C] = l;
                Tth[(size_t)C * m + R] = h;
                Ttl[(size_t)C * m + R] = l;
            }
    }
    gbar(cnt, NB * 2);

    // ---- P2..: remaining levels ----
    short* As0 = (short*)ldsraw;
    short* As1 = As0 + 2048;
    short* Bs0 = As1 + 2048;
    short* Bs1 = Bs0 + 2048;
    unsigned phase = 2;
    for (int s = 128; s < m; s <<= 1) {
        int tilesX = s / 64;
        int ntiles = tilesX * tilesX * (m / (2 * s));
        if (bid < ntiles) {
            int ctt = bid % tilesX, r0t = (bid / tilesX) % tilesX, p = bid / (tilesX * tilesX);
            trimm_tile<1>(As0, As1, Bs0, Bs1, Gh, Gl, Tth, Ttl,
                          tmph, tmpl, nullptr, nullptr, m, s, p, r0t, ctt);
        }
        gbar(cnt, NB * (++phase));
        if (bid < ntiles) {
            int ctt = bid % tilesX, r0t = (bid / tilesX) % tilesX, p = bid / (tilesX * tilesX);
            trimm_tile<2>(As0, As1, Bs0, Bs1, Th, Tl, tmph, tmpl,
                          Th, Tl, Tth, Ttl, m, s, p, r0t, ctt);
        }
        gbar(cnt, NB * (++phase));
    }
}

// out = xh * Qt^T + bias. Round-6-verified apply (unchanged).
__global__ __launch_bounds__(256) void k_apply3(const short* __restrict__ xh,
                                                const short* __restrict__ Qt,
                                                const float* __restrict__ bias,
                                                float* __restrict__ out, int dim) {
    __shared__ short As[128 * 64];
    __shared__ short Bs[128 * 64];
    int nwg = gridDim.x * gridDim.y;
    int flat = blockIdx.y * gridDim.x + blockIdx.x;
    int cpx = nwg >> 3;
    int L = (flat & 7) * cpx + (flat >> 3);   // bijective: nwg % 8 == 0
    int m0 = (L / gridDim.x) * 128, n0 = (L % gridDim.x) * 128;
    int t = threadIdx.x, lane = t & 63, wave = t >> 6;
    int wr = wave >> 1, wc = wave & 1;
    int sr = lane >> 3;
    int sslot = (lane & 7) ^ (sr & 7);
    f32x4 acc[4][4] = {};
    for (int k0 = 0; k0 < dim; k0 += 64) {
        __syncthreads();
#pragma unroll
        for (int q = 0; q < 4; ++q) {
            int rg = wave * 4 + q;
            int row = rg * 8 + sr;
            const short* gA = &xh[(size_t)(m0 + row) * dim + k0 + sslot * 8];
            const short* gB = &Qt[(size_t)(n0 + row) * dim + k0 + sslot * 8];
            __builtin_amdgcn_global_load_lds(
                (const __attribute__((address_space(1))) void*)gA,
                (__attribute__((address_space(3))) void*)&As[rg * 8 * 64], 16, 0, 0);
            __builtin_amdgcn_global_load_lds(
                (const __attribute__((address_space(1))) void*)gB,
                (__attribute__((address_space(3))) void*)&Bs[rg * 8 * 64], 16, 0, 0);
        }
        __syncthreads();
#pragma unroll
        for (int kk = 0; kk < 2; ++kk) {
            int g = kk * 4 + (lane >> 4);
            short8 af[4], bf_[4];
#pragma unroll
            for (int i = 0; i < 4; ++i)
                af[i] = *(const short8*)&As[swz64(wr * 64 + i * 16 + (lane & 15), g)];
#pragma unroll
            for (int j = 0; j < 4; ++j)
                bf_[j] = *(const short8*)&Bs[swz64(wc * 64 + j * 16 + (lane & 15), g)];
#pragma unroll
            for (int i = 0; i < 4; ++i)
#pragma unroll
                for (int j = 0; j < 4; ++j)
                    acc[i][j] = __builtin_amdgcn_mfma_f32_16x16x32_bf16(af[i], bf_[j], acc[i][j], 0, 0, 0);
        }
    }
#pragma unroll
    for (int i = 0; i < 4; ++i)
#pragma unroll
        for (int j = 0; j < 4; ++j) {
            int row = m0 + wr * 64 + i * 16 + (lane >> 4) * 4;
            int col = n0 + wc * 64 + j * 16 + (lane & 15);
            float b = bias[col];
#pragma unroll
            for (int r = 0; r < 4; ++r)
                out[(size_t)(row + r) * dim + col] = acc[i][j][r] + b;
        }
}

extern "C" void kernel_launch(void* const* d_in, const int* in_sizes, int n_in,
                              void* d_out, int out_size, void* d_ws, size_t ws_size,
                              hipStream_t stream) {
    const float* x = (const float*)d_in[0];
    const float* vec = (const float*)d_in[1];
    const float* bias = (const float*)d_in[2];
    float* out = (float*)d_out;

    int dim = in_sizes[2];
    int m = in_sizes[1] / dim;
    int n = in_sizes[0] / dim;

    const size_t MD = (size_t)m * dim;
    const size_t MM = (size_t)m * m;

    char* cur = (char*)d_ws;
    auto alloc_f = [&](size_t nelem) { float* p = (float*)cur; cur += nelem * 4; return p; };
    auto alloc_s = [&](size_t nelem) { short* p = (short*)cur; cur += nelem * 2; return p; };
    float* G   = alloc_f(MM);
    unsigned* cnt = (unsigned*)alloc_f(4);
    short* Vh  = alloc_s(MD);
    short* Vth = alloc_s(MD);
    short* Gh  = alloc_s(MM);
    short* Gl  = alloc_s(MM);
    short* Th  = alloc_s(MM);
    short* Tl  = alloc_s(MM);
    short* Tth = alloc_s(MM);
    short* Ttl = alloc_s(MM);
    short* Wh  = alloc_s(MD);
    short* Qt  = alloc_s((size_t)dim * dim);
    short* tmph = alloc_s(MM / 2);
    short* tmpl = alloc_s(MM / 2);
    short* xh  = alloc_s((size_t)n * dim);

    int gw = m / 64;
    int nTiles = gw * gw;
    int castN4 = (int)((size_t)n * dim / 4);

    // fused norms + scale + bf16 cast (row-major + transposed)
    k_prepall<<<m / 8, 256, 0, stream>>>(vec, Vh, Vth, m, dim);

    // G = V * V^T (upper-triangle tiles, 1 chain) + fused xh cast; zeroes cnt
    k_nt64pc<3, 2, 1><<<nTiles + 512, 256, 0, stream>>>(Vh, nullptr, Vh, nullptr, G, Gh, Gl,
                                                        dim, dim, dim, m, gw, nTiles,
                                                        x, xh, castN4, cnt);
    // entire inversion tree in one kernel (grid barriers between phases)
    k_tree_all<<<(m / 64) * 16, 256, 0, stream>>>(G, Gh, Gl, Th, Tl, Tth, Ttl,
                                                  tmph, tmpl, cnt, m);

    // W[d][k] = sum_{j<=k} Vt[d][j] * Tt[k][j]  (2 chains)
    k_nt64pc<1, 1, 2><<<(m / 64) * (dim / 64), 256, 0, stream>>>(Vth, nullptr, Tth, Ttl, nullptr, Wh, nullptr,
                                                                 m, m, m, m, m / 64, (m / 64) * (dim / 64),
                                                                 nullptr, nullptr, 0, nullptr);
    // Qt[e][d] = delta - sum_k Vt[e][k] * W[d][k]  (1 chain)
    k_nt64pc<2, 0, 1><<<(dim / 64) * (dim / 64), 256, 0, stream>>>(Vth, nullptr, Wh, nullptr, nullptr, Qt, nullptr,
                                                                   m, m, m, dim, dim / 64, (dim / 64) * (dim / 64),
                                                                   nullptr, nullptr, 0, nullptr);

    // out = xh * Qt^T + bias
    k_apply3<<<dim3(dim / 128, n / 128), 256, 0, stream>>>(xh, Qt, bias, out, dim);
}

// Round 12
// 149.813 us; speedup vs baseline: 3.5716x; 3.5716x over previous
//
#include <hip/hip_runtime.h>
#include <hip/hip_bf16.h>

typedef __attribute__((ext_vector_type(8))) short short8;
typedef __attribute__((ext_vector_type(4))) short s16x4;
typedef __attribute__((ext_vector_type(4))) float f32x4;

// fp32 -> bf16 bits, round-to-nearest-even
static __device__ inline short f2bf(float f) {
    unsigned u = __float_as_uint(f);
    unsigned r = (u + 0x7fffu + ((u >> 16) & 1u)) >> 16;
    return (short)r;
}
static __device__ inline float bf2f(short h) {
    return __uint_as_float(((unsigned)(unsigned short)h) << 16);
}

// Swizzled LDS short-offset for 32-short (64B) rows; 16B slot in 0..3.
static __device__ inline int swz32(int row, int slot) {
    return row * 32 + ((slot ^ ((row >> 1) & 3)) << 3);
}
// For 64-short (128B) rows; 16B slot in 0..7.
static __device__ inline int swz64(int row, int slot) {
    return row * 64 + ((slot ^ (row & 7)) << 3);
}

// Fused: row norms + scale + bf16 cast, row-major and transposed writes.
__global__ __launch_bounds__(256) void k_prepall(const float* __restrict__ vec,
                                                 short* __restrict__ Vh,
                                                 short* __restrict__ Vth,
                                                 int m, int dim) {
    __shared__ float tile[8][1028];
    __shared__ float ps[8][32];
    __shared__ float invs[8];
    int r0 = blockIdx.x * 8;
    int t = threadIdx.x;
    int rt = t >> 5, ct = t & 31;
    float ss = 0.f;
#pragma unroll
    for (int p = 0; p < 8; ++p) {
        int c = p * 128 + ct * 4;
        float4 v = *(const float4*)&vec[(size_t)(r0 + rt) * dim + c];
        *(float4*)&tile[rt][c] = v;
        ss += v.x * v.x + v.y * v.y + v.z * v.z + v.w * v.w;
    }
    ps[rt][ct] = ss;
    __syncthreads();
    if (t < 8) {
        float s = 0.f;
#pragma unroll
        for (int q = 0; q < 32; ++q) s += ps[t][q];
        invs[t] = 1.0f / sqrtf(s);
    }
    __syncthreads();
    float iv = invs[rt];
#pragma unroll
    for (int p = 0; p < 8; ++p) {
        int c = p * 128 + ct * 4;
        s16x4 h;
#pragma unroll
        for (int q = 0; q < 4; ++q) h[q] = f2bf(tile[rt][c + q] * iv);
        *(s16x4*)&Vh[(size_t)(r0 + rt) * dim + c] = h;
    }
#pragma unroll
    for (int cc = 0; cc < 4; ++cc) {
        int c = t * 4 + cc;
        s16x4 h0, h1;
#pragma unroll
        for (int r = 0; r < 4; ++r) h0[r] = f2bf(tile[r][c] * invs[r]);
#pragma unroll
        for (int r = 0; r < 4; ++r) h1[r] = f2bf(tile[4 + r][c] * invs[4 + r]);
        *(s16x4*)&Vth[(size_t)c * m + r0] = h0;
        *(s16x4*)&Vth[(size_t)c * m + r0 + 4] = h1;
    }
}

// 64x64-tile NT GEMM, bf16 operands, register-prefetch double buffering.
// CH = number of MFMA chains. MODE 1: write Ch. MODE 2: Ch = bf16(delta-acc).
// MODE 3: Cf + Ch/Cl split. TRI 0: full K. TRI 1: K-bound = j0+64.
// TRI 2: upper-triangle tiles only, enumerated directly (no dead blocks).
// Blocks >= nTiles run the fused fp32->bf16 cast.
template<int MODE, int TRI, int CH>
__global__ __launch_bounds__(256) void k_nt64pc(
    const short* __restrict__ Ah, const short* __restrict__ Al,
    const short* __restrict__ Bh, const short* __restrict__ Bl,
    float* __restrict__ Cf, short* __restrict__ Ch, short* __restrict__ Cl,
    int K, int lda, int ldb, int ldc, int gw, int nTiles,
    const float* __restrict__ castX, short* __restrict__ castXh, int castN4) {
    __shared__ short As[2][2][64 * 32];
    __shared__ short Bs[2][2][64 * 32];
    int flat = blockIdx.x;
    if (flat >= nTiles) {
        int idx = (flat - nTiles) * 256 + threadIdx.x;
        int stride = (gridDim.x - nTiles) * 256;
        for (int i = idx; i < castN4; i += stride) {
            float4 v = ((const float4*)castX)[i];
            float f[4] = {v.x, v.y, v.z, v.w};
            s16x4 h;
#pragma unroll
            for (int q = 0; q < 4; ++q) h[q] = f2bf(f[q]);
            *(s16x4*)&castXh[(size_t)i * 4] = h;
        }
        return;
    }
    int ti, tj;
    if (TRI == 2) {
        // triangular decode: row r has (gw - r) tiles, j >= i
        int f = flat, i = 0;
        while (f >= gw - i) { f -= gw - i; ++i; }
        ti = i; tj = i + f;
    } else {
        ti = flat / gw; tj = flat % gw;
    }
    int i0 = ti * 64, j0 = tj * 64;
    int KE = (TRI == 1) ? (j0 + 64) : K;
    int t = threadIdx.x, lane = t & 63, wave = t >> 6;
    int wr = wave >> 1, wc = wave & 1;
    int srow = t >> 2, slot = t & 3;
    int sofs = swz32(srow, slot);
    int gofs = slot * 8;
    const short* gA_h = &Ah[(size_t)(i0 + srow) * lda + gofs];
    const short* gA_l = (CH >= 3) ? &Al[(size_t)(i0 + srow) * lda + gofs] : nullptr;
    const short* gB_h = &Bh[(size_t)(j0 + srow) * ldb + gofs];
    const short* gB_l = (CH >= 2) ? &Bl[(size_t)(j0 + srow) * ldb + gofs] : nullptr;
    short8 pAh = *(const short8*)&gA_h[0];
    short8 pAl, pBl;
    short8 pBh = *(const short8*)&gB_h[0];
    if (CH >= 2) pBl = *(const short8*)&gB_l[0];
    if (CH >= 3) pAl = *(const short8*)&gA_l[0];
    *(short8*)&As[0][0][sofs] = pAh;
    *(short8*)&Bs[0][0][sofs] = pBh;
    if (CH >= 2) *(short8*)&Bs[0][1][sofs] = pBl;
    if (CH >= 3) *(short8*)&As[0][1][sofs] = pAl;
    f32x4 acc[2][2] = {};
    int nIter = KE >> 5;
    int cur = 0;
    for (int it = 0; it < nIter; ++it) {
        __syncthreads();
        int kn = (it + 1) << 5;
        bool have = kn < KE;
        if (have) {
            pAh = *(const short8*)&gA_h[kn];
            pBh = *(const short8*)&gB_h[kn];
            if (CH >= 2) pBl = *(const short8*)&gB_l[kn];
            if (CH >= 3) pAl = *(const short8*)&gA_l[kn];
        }
        int g = lane >> 4;
        short8 ah[2], al2[2], bh[2], bl2[2];
#pragma unroll
        for (int i = 0; i < 2; ++i) {
            int ro = swz32(wr * 32 + i * 16 + (lane & 15), g);
            ah[i] = *(const short8*)&As[cur][0][ro];
            if (CH >= 3) al2[i] = *(const short8*)&As[cur][1][ro];
        }
#pragma unroll
        for (int j = 0; j < 2; ++j) {
            int ro = swz32(wc * 32 + j * 16 + (lane & 15), g);
            bh[j] = *(const short8*)&Bs[cur][0][ro];
            if (CH >= 2) bl2[j] = *(const short8*)&Bs[cur][1][ro];
        }
#pragma unroll
        for (int i = 0; i < 2; ++i)
#pragma unroll
            for (int j = 0; j < 2; ++j) {
                acc[i][j] = __builtin_amdgcn_mfma_f32_16x16x32_bf16(ah[i], bh[j], acc[i][j], 0, 0, 0);
                if (CH >= 2)
                    acc[i][j] = __builtin_amdgcn_mfma_f32_16x16x32_bf16(ah[i], bl2[j], acc[i][j], 0, 0, 0);
                if (CH >= 3)
                    acc[i][j] = __builtin_amdgcn_mfma_f32_16x16x32_bf16(al2[i], bh[j], acc[i][j], 0, 0, 0);
            }
        if (have) {
            *(short8*)&As[cur ^ 1][0][sofs] = pAh;
            *(short8*)&Bs[cur ^ 1][0][sofs] = pBh;
            if (CH >= 2) *(short8*)&Bs[cur ^ 1][1][sofs] = pBl;
            if (CH >= 3) *(short8*)&As[cur ^ 1][1][sofs] = pAl;
        }
        cur ^= 1;
    }
#pragma unroll
    for (int i = 0; i < 2; ++i)
#pragma unroll
        for (int j = 0; j < 2; ++j) {
            int row0 = i0 + wr * 32 + i * 16 + ((lane >> 4) << 2);
            int col = j0 + wc * 32 + j * 16 + (lane & 15);
#pragma unroll
            for (int r = 0; r < 4; ++r) {
                float v = acc[i][j][r];
                size_t idx = (size_t)(row0 + r) * ldc + col;
                if (MODE == 2) {
                    Ch[idx] = f2bf((((row0 + r) == col) ? 1.f : 0.f) - v);
                } else if (MODE == 1) {
                    Ch[idx] = f2bf(v);
                } else {
                    short h = f2bf(v);
                    Ch[idx] = h;
                    Cl[idx] = f2bf(v - bf2f(h));
                    Cf[idx] = v;
                }
            }
        }
}

// Parallel inversion of 64x64 diagonal blocks of R = 0.5 I + striu(G).
__global__ __launch_bounds__(256) void k_baseinv2(const float* __restrict__ G,
                                                  short* __restrict__ Th, short* __restrict__ Tl,
                                                  short* __restrict__ Tth, short* __restrict__ Ttl,
                                                  int m) {
    __shared__ float Rs[64 * 64];
    int d = blockIdx.x >> 4, g = blockIdx.x & 15;
    int b0 = d * 64;
    int t = threadIdx.x, lane = t & 63, wave = t >> 6;
    {
        int r = t >> 2, c00 = (t & 3) * 16;
#pragma unroll
        for (int q = 0; q < 4; ++q)
            *(float4*)&Rs[r * 64 + c00 + q * 4] =
                *(const float4*)&G[(size_t)(b0 + r) * m + b0 + c00 + q * 4];
    }
    __syncthreads();
    int c = g * 4 + wave;
    float x = 0.f;
    for (int r = c; r >= 0; --r) {
        float prod = Rs[r * 64 + lane] * x;
        float s = prod;
#pragma unroll
        for (int off = 32; off; off >>= 1) s += __shfl_xor(s, off, 64);
        if (lane == r) x = ((r == c) ? 2.f : 0.f) - 2.f * s;
    }
    short h = f2bf(x);
    short l = f2bf(x - bf2f(h));
    Th[(size_t)(b0 + lane) * m + b0 + c] = h;
    Tl[(size_t)(b0 + lane) * m + b0 + c] = l;
    Tth[(size_t)(b0 + c) * m + b0 + lane] = h;
    Ttl[(size_t)(b0 + c) * m + b0 + lane] = l;
}

// Fused s=64 tree level: T[a0..,c0..] = -Ainv * (G_B * Cinv).
__global__ __launch_bounds__(256) void k_tree64f(const float* __restrict__ G,
                                                 short* __restrict__ Th, short* __restrict__ Tl,
                                                 short* __restrict__ Tth, short* __restrict__ Ttl,
                                                 int m) {
    __shared__ float Gb[64 * 65];
    __shared__ float Ai[64 * 65];
    __shared__ float Ci[64 * 64];
    __shared__ float Tm[64 * 64];
    int p = blockIdx.x;
    int a0 = p * 128, c0 = a0 + 64;
    int t = threadIdx.x;
    {
        int r = t >> 2, c00 = (t & 3) * 16;
#pragma unroll
        for (int q = 0; q < 4; ++q) {
            *(float4*)&Gb[r * 65 + c00 + q * 4] =
                *(const float4*)&G[(size_t)(a0 + r) * m + c0 + c00 + q * 4];
            s16x4 ha = *(const s16x4*)&Th[(size_t)(a0 + r) * m + a0 + c00 + q * 4];
            s16x4 la = *(const s16x4*)&Tl[(size_t)(a0 + r) * m + a0 + c00 + q * 4];
            s16x4 hc = *(const s16x4*)&Th[(size_t)(c0 + r) * m + c0 + c00 + q * 4];
            s16x4 lc = *(const s16x4*)&Tl[(size_t)(c0 + r) * m + c0 + c00 + q * 4];
#pragma unroll
            for (int e = 0; e < 4; ++e) {
                Ai[r * 65 + c00 + q * 4 + e] = bf2f(ha[e]) + bf2f(la[e]);
                Ci[r * 64 + c00 + q * 4 + e] = bf2f(hc[e]) + bf2f(lc[e]);
            }
        }
    }
    __syncthreads();
    int tx = t & 15, ty = t >> 4;
    float acc[4][4] = {};
#pragma unroll 4
    for (int k = 0; k < 64; ++k) {
        float av[4], bv[4];
#pragma unroll
        for (int i = 0; i < 4; ++i) av[i] = Gb[(ty * 4 + i) * 65 + k];
#pragma unroll
        for (int j = 0; j < 4; ++j) bv[j] = Ci[k * 64 + tx * 4 + j];
#pragma unroll
        for (int i = 0; i < 4; ++i)
#pragma unroll
            for (int j = 0; j < 4; ++j) acc[i][j] += av[i] * bv[j];
    }
#pragma unroll
    for (int i = 0; i < 4; ++i)
#pragma unroll
        for (int j = 0; j < 4; ++j) Tm[(ty * 4 + i) * 64 + tx * 4 + j] = acc[i][j];
    __syncthreads();
    float acc2[4][4] = {};
#pragma unroll 4
    for (int k = 0; k < 64; ++k) {
        float av[4], bv[4];
#pragma unroll
        for (int i = 0; i < 4; ++i) av[i] = Ai[(ty * 4 + i) * 65 + k];
#pragma unroll
        for (int j = 0; j < 4; ++j) bv[j] = Tm[k * 64 + tx * 4 + j];
#pragma unroll
        for (int i = 0; i < 4; ++i)
#pragma unroll
            for (int j = 0; j < 4; ++j) acc2[i][j] += av[i] * bv[j];
    }
#pragma unroll
    for (int i = 0; i < 4; ++i)
#pragma unroll
        for (int j = 0; j < 4; ++j) {
            float v = -acc2[i][j];
            short h = f2bf(v);
            short l = f2bf(v - bf2f(h));
            int R = a0 + ty * 4 + i, C = c0 + tx * 4 + j;
            Th[(size_t)R * m + C] = h;
            Tl[(size_t)R * m + C] = l;
            Tth[(size_t)C * m + R] = h;
            Ttl[(size_t)C * m + R] = l;
        }
}

// Tree-level block GEMMs on split operands (NT MFMA, triangular K-bounds).
template<int PHASE>
__global__ __launch_bounds__(256) void k_trimm(
    const short* __restrict__ Ah, const short* __restrict__ Al,
    const short* __restrict__ Bh, const short* __restrict__ Bl,
    short* __restrict__ C1h, short* __restrict__ C1l,
    short* __restrict__ C2h, short* __restrict__ C2l,
    int m, int s) {
    __shared__ short As[2][64 * 32];
    __shared__ short Bs[2][64 * 32];
    int p = blockIdx.z;
    int a0 = 2 * p * s, c0 = a0 + s;
    int r0 = blockIdx.y * 64, ct = blockIdx.x * 64;
    int KS = (PHASE == 1) ? 0 : r0;
    int KE = (PHASE == 1) ? (ct + 64) : s;
    size_t tbase = (size_t)p * s * s;
    int t = threadIdx.x, lane = t & 63, wave = t >> 6;
    int wr = wave >> 1, wc = wave & 1;
    int srow = t >> 2, slot = t & 3;
    int sofs = swz32(srow, slot);
    int gofs = slot * 8;
    f32x4 acc[2][2] = {};
    for (int k0 = KS; k0 < KE; k0 += 32) {
        __syncthreads();
        if (PHASE == 1) {
            *(short8*)&As[0][sofs] = *(const short8*)&Ah[(size_t)(a0 + r0 + srow) * m + c0 + k0 + gofs];
            *(short8*)&As[1][sofs] = *(const short8*)&Al[(size_t)(a0 + r0 + srow) * m + c0 + k0 + gofs];
            *(short8*)&Bs[0][sofs] = *(const short8*)&Bh[(size_t)(c0 + ct + srow) * m + c0 + k0 + gofs];
            *(short8*)&Bs[1][sofs] = *(const short8*)&Bl[(size_t)(c0 + ct + srow) * m + c0 + k0 + gofs];
        } else {
            *(short8*)&As[0][sofs] = *(const short8*)&Ah[(size_t)(a0 + r0 + srow) * m + a0 + k0 + gofs];
            *(short8*)&As[1][sofs] = *(const short8*)&Al[(size_t)(a0 + r0 + srow) * m + a0 + k0 + gofs];
            *(short8*)&Bs[0][sofs] = *(const short8*)&Bh[tbase + (size_t)(ct + srow) * s + k0 + gofs];
            *(short8*)&Bs[1][sofs] = *(const short8*)&Bl[tbase + (size_t)(ct + srow) * s + k0 + gofs];
        }
        __syncthreads();
        int g = lane >> 4;
        short8 ah[2], al2[2], bh[2], bl2[2];
#pragma unroll
        for (int i = 0; i < 2; ++i) {
            int ro = swz32(wr * 32 + i * 16 + (lane & 15), g);
            ah[i] = *(const short8*)&As[0][ro];
            al2[i] = *(const short8*)&As[1][ro];
        }
#pragma unroll
        for (int j = 0; j < 2; ++j) {
            int ro = swz32(wc * 32 + j * 16 + (lane & 15), g);
            bh[j] = *(const short8*)&Bs[0][ro];
            bl2[j] = *(const short8*)&Bs[1][ro];
        }
#pragma unroll
        for (int i = 0; i < 2; ++i)
#pragma unroll
            for (int j = 0; j < 2; ++j) {
                acc[i][j] = __builtin_amdgcn_mfma_f32_16x16x32_bf16(ah[i], bh[j], acc[i][j], 0, 0, 0);
                acc[i][j] = __builtin_amdgcn_mfma_f32_16x16x32_bf16(ah[i], bl2[j], acc[i][j], 0, 0, 0);
                acc[i][j] = __builtin_amdgcn_mfma_f32_16x16x32_bf16(al2[i], bh[j], acc[i][j], 0, 0, 0);
            }
    }
#pragma unroll
    for (int i = 0; i < 2; ++i)
#pragma unroll
        for (int j = 0; j < 2; ++j) {
            int row0 = r0 + wr * 32 + i * 16 + ((lane >> 4) << 2);
            int col = ct + wc * 32 + j * 16 + (lane & 15);
#pragma unroll
            for (int r = 0; r < 4; ++r) {
                if (PHASE == 1) {
                    float v = acc[i][j][r];
                    short h = f2bf(v);
                    short l = f2bf(v - bf2f(h));
                    size_t idx = tbase + (size_t)col * s + row0 + r;
                    C1h[idx] = h;
                    C1l[idx] = l;
                } else {
                    float v = -acc[i][j][r];
                    short h = f2bf(v);
                    short l = f2bf(v - bf2f(h));
                    int R = a0 + row0 + r, Cc = c0 + col;
                    C1h[(size_t)R * m + Cc] = h;
                    C1l[(size_t)R * m + Cc] = l;
                    C2h[(size_t)Cc * m + R] = h;
                    C2l[(size_t)Cc * m + R] = l;
                }
            }
        }
}

// out = xh * Qt^T + bias. Round-6-verified apply (unchanged).
__global__ __launch_bounds__(256) void k_apply3(const short* __restrict__ xh,
                                                const short* __restrict__ Qt,
                                                const float* __restrict__ bias,
                                                float* __restrict__ out, int dim) {
    __shared__ short As[128 * 64];
    __shared__ short Bs[128 * 64];
    int nwg = gridDim.x * gridDim.y;
    int flat = blockIdx.y * gridDim.x + blockIdx.x;
    int cpx = nwg >> 3;
    int L = (flat & 7) * cpx + (flat >> 3);   // bijective: nwg % 8 == 0
    int m0 = (L / gridDim.x) * 128, n0 = (L % gridDim.x) * 128;
    int t = threadIdx.x, lane = t & 63, wave = t >> 6;
    int wr = wave >> 1, wc = wave & 1;
    int sr = lane >> 3;
    int sslot = (lane & 7) ^ (sr & 7);
    f32x4 acc[4][4] = {};
    for (int k0 = 0; k0 < dim; k0 += 64) {
        __syncthreads();
#pragma unroll
        for (int q = 0; q < 4; ++q) {
            int rg = wave * 4 + q;
            int row = rg * 8 + sr;
            const short* gA = &xh[(size_t)(m0 + row) * dim + k0 + sslot * 8];
            const short* gB = &Qt[(size_t)(n0 + row) * dim + k0 + sslot * 8];
            __builtin_amdgcn_global_load_lds(
                (const __attribute__((address_space(1))) void*)gA,
                (__attribute__((address_space(3))) void*)&As[rg * 8 * 64], 16, 0, 0);
            __builtin_amdgcn_global_load_lds(
                (const __attribute__((address_space(1))) void*)gB,
                (__attribute__((address_space(3))) void*)&Bs[rg * 8 * 64], 16, 0, 0);
        }
        __syncthreads();
#pragma unroll
        for (int kk = 0; kk < 2; ++kk) {
            int g = kk * 4 + (lane >> 4);
            short8 af[4], bf_[4];
#pragma unroll
            for (int i = 0; i < 4; ++i)
                af[i] = *(const short8*)&As[swz64(wr * 64 + i * 16 + (lane & 15), g)];
#pragma unroll
            for (int j = 0; j < 4; ++j)
                bf_[j] = *(const short8*)&Bs[swz64(wc * 64 + j * 16 + (lane & 15), g)];
#pragma unroll
            for (int i = 0; i < 4; ++i)
#pragma unroll
                for (int j = 0; j < 4; ++j)
                    acc[i][j] = __builtin_amdgcn_mfma_f32_16x16x32_bf16(af[i], bf_[j], acc[i][j], 0, 0, 0);
        }
    }
#pragma unroll
    for (int i = 0; i < 4; ++i)
#pragma unroll
        for (int j = 0; j < 4; ++j) {
            int row = m0 + wr * 64 + i * 16 + (lane >> 4) * 4;
            int col = n0 + wc * 64 + j * 16 + (lane & 15);
            float b = bias[col];
#pragma unroll
            for (int r = 0; r < 4; ++r)
                out[(size_t)(row + r) * dim + col] = acc[i][j][r] + b;
        }
}

extern "C" void kernel_launch(void* const* d_in, const int* in_sizes, int n_in,
                              void* d_out, int out_size, void* d_ws, size_t ws_size,
                              hipStream_t stream) {
    const float* x = (const float*)d_in[0];
    const float* vec = (const float*)d_in[1];
    const float* bias = (const float*)d_in[2];
    float* out = (float*)d_out;

    int dim = in_sizes[2];
    int m = in_sizes[1] / dim;
    int n = in_sizes[0] / dim;

    const size_t MD = (size_t)m * dim;
    const size_t MM = (size_t)m * m;

    char* cur = (char*)d_ws;
    auto alloc_f = [&](size_t nelem) { float* p = (float*)cur; cur += nelem * 4; return p; };
    auto alloc_s = [&](size_t nelem) { short* p = (short*)cur; cur += nelem * 2; return p; };
    float* G   = alloc_f(MM);
    short* Vh  = alloc_s(MD);
    short* Vth = alloc_s(MD);
    short* Gh  = alloc_s(MM);
    short* Gl  = alloc_s(MM);
    short* Th  = alloc_s(MM);
    short* Tl  = alloc_s(MM);
    short* Tth = alloc_s(MM);
    short* Ttl = alloc_s(MM);
    short* Wh  = alloc_s(MD);
    short* Qt  = alloc_s((size_t)dim * dim);
    short* tmph = alloc_s(MM / 2);
    short* tmpl = alloc_s(MM / 2);
    short* xh  = alloc_s((size_t)n * dim);

    int gw = m / 64;
    int nTilesTri = gw * (gw + 1) / 2;   // upper-triangle tiles only
    int castN4 = (int)((size_t)n * dim / 4);

    // fused norms + scale + bf16 cast (row-major + transposed)
    k_prepall<<<m / 8, 256, 0, stream>>>(vec, Vh, Vth, m, dim);

    // G = V * V^T (upper-triangle tiles, 1 chain) + fused xh cast on extra blocks
    k_nt64pc<3, 2, 1><<<nTilesTri + 512, 256, 0, stream>>>(Vh, nullptr, Vh, nullptr, G, Gh, Gl,
                                                           dim, dim, dim, m, gw, nTilesTri,
                                                           x, xh, castN4);
    // diag-block inversion -> split T (row-major + transposed)
    k_baseinv2<<<(m / 64) * 16, 256, 0, stream>>>(G, Th, Tl, Tth, Ttl, m);
    // s=64 tree level fused in-LDS
    k_tree64f<<<m / 128, 256, 0, stream>>>(G, Th, Tl, Tth, Ttl, m);
    // remaining tree levels, MFMA on split operands
    for (int s = 128; s < m; s <<= 1) {
        dim3 g(s / 64, s / 64, m / (2 * s));
        k_trimm<1><<<g, 256, 0, stream>>>(Gh, Gl, Tth, Ttl, tmph, tmpl, nullptr, nullptr, m, s);
        k_trimm<2><<<g, 256, 0, stream>>>(Th, Tl, tmph, tmpl, Th, Tl, Tth, Ttl, m, s);
    }

    // W[d][k] = sum_{j<=k} Vt[d][j] * Tt[k][j]  (2 chains)
    k_nt64pc<1, 1, 2><<<(m / 64) * (dim / 64), 256, 0, stream>>>(Vth, nullptr, Tth, Ttl, nullptr, Wh, nullptr,
                                                                 m, m, m, m, m / 64, (m / 64) * (dim / 64),
                                                                 nullptr, nullptr, 0);
    // Qt[e][d] = delta - sum_k Vt[e][k] * W[d][k]  (1 chain)
    k_nt64pc<2, 0, 1><<<(dim / 64) * (dim / 64), 256, 0, stream>>>(Vth, nullptr, Wh, nullptr, nullptr, Qt, nullptr,
                                                                   m, m, m, dim, dim / 64, (dim / 64) * (dim / 64),
                                                                   nullptr, nullptr, 0);

    // out = xh * Qt^T + bias
    k_apply3<<<dim3(dim / 128, n / 128), 256, 0, stream>>>(xh, Qt, bias, out, dim);
}